// Round 6
// baseline (67.423 us; speedup 1.0000x reference)
//
#include <hip/hip_runtime.h>
#include <hip/hip_bf16.h>

// Problem constants
#define B_  64
#define N1_ 8
#define KK  128
#define EE  256
#define HH  512
#define BN  (B_ * N1_)   // 512

typedef __attribute__((ext_vector_type(8))) short short8;   // bf16x8 MFMA frag
typedef __attribute__((ext_vector_type(4))) float f32x4;    // MFMA acc

__device__ __forceinline__ short bfs(float f) {
  __hip_bfloat16 h = __float2bfloat16(f);   // RNE
  return __builtin_bit_cast(short, h);
}

__device__ __forceinline__ float tanhf_fast(float x) {
  // tanh(x) = 1 - 2/(exp(2x)+1);  exp(2x) = exp2(2*log2e*x)
  float e2 = __builtin_amdgcn_exp2f(2.8853900817779268f * x);
  return 1.0f - 2.0f * __builtin_amdgcn_rcpf(e2 + 1.0f);
}

// ---------------------------------------------------------------------------
// k_prep: convert wk_w and wq_w (each 512x256 f32) to bf16. 256 blocks.
// ---------------------------------------------------------------------------
__global__ __launch_bounds__(256) void k_prep(
    const float* __restrict__ wk_w, const float* __restrict__ wq_w,
    unsigned short* __restrict__ wk_bf, unsigned short* __restrict__ wq_bf) {
  const int bid = blockIdx.x, t = threadIdx.x;
  const float* src = (bid < 128) ? wk_w : wq_w;
  unsigned short* dst = (bid < 128) ? wk_bf : wq_bf;
  const int i = ((bid & 127) * 256 + t) * 4;
  float4 v = *(const float4*)(src + i);
  union { unsigned short u[4]; uint2 p; } pk;
  pk.u[0] = (unsigned short)bfs(v.x);
  pk.u[1] = (unsigned short)bfs(v.y);
  pk.u[2] = (unsigned short)bfs(v.z);
  pk.u[3] = (unsigned short)bfs(v.w);
  *(uint2*)(dst + i) = pk.p;
}

// ---------------------------------------------------------------------------
// k_qproj (MFMA): qp[bn][h] = dot(queries[bn,:], wq[h,:]) + wq_b[h] + wk_b[h]
// 32 blocks x 4 waves; block = 16 bn-rows, wave w = h-range [w*128, w*128+128).
// Same fragment layout as k_fused's GEMM (A row = ll, e = lg*8 + s*32;
// D: col(h)=ll, row(bn)=lg*4+r)  [m89].
// ---------------------------------------------------------------------------
__global__ __launch_bounds__(256) void k_qproj(
    const float* __restrict__ queries,
    const unsigned short* __restrict__ wq_bf,
    const float* __restrict__ wq_b,
    const float* __restrict__ wk_b,
    float* __restrict__ qp) {
  const int t = threadIdx.x, w = t >> 6, l = t & 63;
  const int lg = l >> 4, ll = l & 15;
  const int bn0 = blockIdx.x * 16;

  short8 af[8];
  {
    const float* qr = queries + (size_t)(bn0 + ll) * EE + lg * 8;
    #pragma unroll
    for (int s = 0; s < 8; ++s) {
      float4 x = *(const float4*)(qr + s * 32);
      float4 y = *(const float4*)(qr + s * 32 + 4);
      short8 f;
      f[0] = bfs(x.x); f[1] = bfs(x.y); f[2] = bfs(x.z); f[3] = bfs(x.w);
      f[4] = bfs(y.x); f[5] = bfs(y.y); f[6] = bfs(y.z); f[7] = bfs(y.w);
      af[s] = f;
    }
  }
  #pragma unroll
  for (int i = 0; i < 8; ++i) {
    const int h0 = w * 128 + i * 16;
    const unsigned short* bp = wq_bf + (size_t)(h0 + ll) * EE + lg * 8;
    f32x4 a = {0.f, 0.f, 0.f, 0.f};
    #pragma unroll
    for (int s = 0; s < 8; ++s) {
      short8 bfr = *(const short8*)(bp + s * 32);
      a = __builtin_amdgcn_mfma_f32_16x16x32_bf16(af[s], bfr, a, 0, 0, 0);
    }
    const int h = h0 + ll;
    const float add = wq_b[h] + wk_b[h];
    #pragma unroll
    for (int r = 0; r < 4; ++r)
      qp[(size_t)(bn0 + lg * 4 + r) * HH + h] = a[r] + add;
  }
}

// ---------------------------------------------------------------------------
// k_fused: one block = one bn (128 key-rows), 8 waves = 4 row-grp x 2 h-half.
// Wave (rg,hh): rows rg*32..+31 (2 MFMA chains), h-half hh*256..+255.
// Per step i (0..15): both halves' wk tiles (i and 16+i) live in LDS
// (2 x 8 KB, XOR-swizzled, double-buffered). Each tile read by 4 waves.
// Then scores -> masked softmax -> attn_weight + attn_out in-block.
// MFMA 16x16x32 C/D: col(h)=lane&15, row(key)=(lane>>4)*4+reg   [m89].
// __launch_bounds__(512,4): cap VGPR at 128 so 2 blocks/CU co-reside.
// ---------------------------------------------------------------------------
__global__ __launch_bounds__(512, 4) void k_fused(
    const float* __restrict__ keys,
    const unsigned short* __restrict__ wk_bf,
    const float* __restrict__ wv_w,
    const float* __restrict__ qp,
    const int* __restrict__ masks,
    float* __restrict__ out) {
  const int t  = threadIdx.x;
  const int w  = t >> 6;      // wave 0..7
  const int l  = t & 63;
  const int lg = l >> 4;      // lane group 0..3
  const int ll = l & 15;
  const int rg = w & 3;       // row group (32 rows)
  const int hh = w >> 2;      // h half
  const int bn = blockIdx.x;

  __shared__ __align__(16) char bsm[2][2 * 8192];  // [buf][half tile 8KB]
  __shared__ float qb_s[HH];
  __shared__ float wv_s[HH];
  __shared__ float sc2[2][KK];
  __shared__ float sc[KK];
  __shared__ float po[512];
  __shared__ float red[2];

  // --- keys for this wave's 32 rows -> bf16 A-frags (2 chains x 8) ---
  short8 af0[8], af1[8];
  {
    const float* kp0 = keys + (size_t)(bn * KK + rg * 32 + ll) * EE + lg * 8;
    const float* kp1 = kp0 + 16 * EE;
    #pragma unroll
    for (int s = 0; s < 8; ++s) {
      float4 x = *(const float4*)(kp0 + s * 32);
      float4 y = *(const float4*)(kp0 + s * 32 + 4);
      short8 f;
      f[0] = bfs(x.x); f[1] = bfs(x.y); f[2] = bfs(x.z); f[3] = bfs(x.w);
      f[4] = bfs(y.x); f[5] = bfs(y.y); f[6] = bfs(y.z); f[7] = bfs(y.w);
      af0[s] = f;
      x = *(const float4*)(kp1 + s * 32);
      y = *(const float4*)(kp1 + s * 32 + 4);
      f[0] = bfs(x.x); f[1] = bfs(x.y); f[2] = bfs(x.z); f[3] = bfs(x.w);
      f[4] = bfs(y.x); f[5] = bfs(y.y); f[6] = bfs(y.z); f[7] = bfs(y.w);
      af1[s] = f;
    }
  }

  // per-block scalars
  qb_s[t] = qp[(size_t)bn * HH + t];
  wv_s[t] = wv_w[t];

  // wk staging: 512 threads x 16B chunk per half-tile
  const char* wkb = (const char*)wk_bf;             // 512 rows x 512 B
  const int hl = t >> 5;                             // h-local 0..15
  const int of = (t & 31) * 16;
  const int dsw  = hl * 512 + (of ^ ((hl & 7) << 4));
  const int gof  = hl * 512 + of;

  // prologue: stage tiles (0, 16) into buf 0
  {
    int4 a0 = *(const int4*)(wkb + gof);                    // tile 0
    int4 a1 = *(const int4*)(wkb + 16 * 8192 + gof);        // tile 16
    *(int4*)(bsm[0] + dsw) = a0;
    *(int4*)(bsm[0] + 8192 + dsw) = a1;
  }
  __syncthreads();

  float p0[4] = {0.f, 0.f, 0.f, 0.f};
  float p1[4] = {0.f, 0.f, 0.f, 0.f};

  for (int i = 0; i < 16; ++i) {
    int4 n0, n1;
    if (i < 15) {
      n0 = *(const int4*)(wkb + (size_t)(i + 1) * 8192 + gof);
      n1 = *(const int4*)(wkb + (size_t)(17 + i) * 8192 + gof);
    }

    const char* buf = bsm[i & 1] + hh * 8192;
    f32x4 a0 = {0.f, 0.f, 0.f, 0.f};
    f32x4 a1 = {0.f, 0.f, 0.f, 0.f};
    #pragma unroll
    for (int s = 0; s < 8; ++s) {
      int off = (lg * 16 + s * 64) ^ ((ll & 7) << 4);
      short8 bfr = *(const short8*)(buf + ll * 512 + off);
      a0 = __builtin_amdgcn_mfma_f32_16x16x32_bf16(af0[s], bfr, a0, 0, 0, 0);
      a1 = __builtin_amdgcn_mfma_f32_16x16x32_bf16(af1[s], bfr, a1, 0, 0, 0);
    }

    const int h = hh * 256 + i * 16 + ll;
    const float qb = qb_s[h];
    const float wv = wv_s[h];
    #pragma unroll
    for (int r = 0; r < 4; ++r) p0[r] += wv * tanhf_fast(a0[r] + qb);
    #pragma unroll
    for (int r = 0; r < 4; ++r) p1[r] += wv * tanhf_fast(a1[r] + qb);

    if (i < 15) {
      char* nb = bsm[(i + 1) & 1];
      *(int4*)(nb + dsw) = n0;
      *(int4*)(nb + 8192 + dsw) = n1;
    }
    __syncthreads();
  }

  // reduce over h within lane-group (16 ll lanes)
  #pragma unroll
  for (int r = 0; r < 4; ++r) {
    #pragma unroll
    for (int off = 1; off <= 8; off <<= 1) {
      p0[r] += __shfl_xor(p0[r], off, 64);
      p1[r] += __shfl_xor(p1[r], off, 64);
    }
  }
  if (ll == 0) {
    #pragma unroll
    for (int r = 0; r < 4; ++r) {
      sc2[hh][rg * 32 + lg * 4 + r]      = p0[r];
      sc2[hh][rg * 32 + 16 + lg * 4 + r] = p1[r];
    }
  }
  __syncthreads();

  // masked softmax over K=128 (wv_b omitted: softmax shift-invariant)
  if (t < KK)
    sc[t] = sc2[0][t] + sc2[1][t] + (float)masks[bn * KK + t] * (-1e9f);
  __syncthreads();
  if (t < 64) {
    float a = fmaxf(sc[t], sc[t + 64]);
    #pragma unroll
    for (int off = 32; off >= 1; off >>= 1) a = fmaxf(a, __shfl_xor(a, off, 64));
    if (t == 0) red[0] = a;
  }
  __syncthreads();
  const float m = red[0];
  if (t < KK) sc[t] = expf(sc[t] - m);
  __syncthreads();
  if (t < 64) {
    float a = sc[t] + sc[t + 64];
    #pragma unroll
    for (int off = 32; off >= 1; off >>= 1) a += __shfl_xor(a, off, 64);
    if (t == 0) red[1] = a;
  }
  __syncthreads();
  const float inv = 1.f / red[1];
  if (t < KK) {
    float wgt = sc[t] * inv;
    sc[t] = wgt;
    out[BN * EE + (size_t)bn * KK + t] = wgt;   // attn_weight
  }
  __syncthreads();

  // attn_out[bn][e] = sum_k w[k]*keys[bn,k,e]; k split across thread halves
  const int e = t & 255, kh = t >> 8;
  const float* kb = keys + (size_t)bn * KK * EE + (size_t)kh * 64 * EE;
  float acc = 0.f;
  #pragma unroll 8
  for (int k = 0; k < 64; ++k)
    acc += sc[kh * 64 + k] * kb[k * EE + e];    // coalesced over e
  po[t] = acc;
  __syncthreads();
  if (t < 256) out[(size_t)bn * EE + t] = po[t] + po[t + 256];
}

// ---------------------------------------------------------------------------
extern "C" void kernel_launch(void* const* d_in, const int* in_sizes, int n_in,
                              void* d_out, int out_size, void* d_ws, size_t ws_size,
                              hipStream_t stream) {
  const float* queries = (const float*)d_in[0];
  const float* keys    = (const float*)d_in[1];
  const int*   masks   = (const int*)d_in[2];
  // d_in[3] = num_neg (unused)
  const float* wk_w = (const float*)d_in[4];
  const float* wk_b = (const float*)d_in[5];
  const float* wq_w = (const float*)d_in[6];
  const float* wq_b = (const float*)d_in[7];
  const float* wv_w = (const float*)d_in[8];
  // d_in[9] = wv_b (softmax shift-invariant -> unused)

  float* out = (float*)d_out;
  float* qp  = (float*)d_ws;                                // 512*512 f32 = 1 MB
  unsigned short* wk_bf = (unsigned short*)(qp + BN * HH);  // 256 KB
  unsigned short* wq_bf = wk_bf + HH * EE;                  // 256 KB

  k_prep<<<256, 256, 0, stream>>>(wk_w, wq_w, wk_bf, wq_bf);
  k_qproj<<<32, 256, 0, stream>>>(queries, wq_bf, wq_b, wk_b, qp);
  k_fused<<<BN, 512, 0, stream>>>(keys, wk_bf, wv_w, qp, masks, out);
}